// Round 5
// baseline (56.043 us; speedup 1.0000x reference)
//
#include <hip/hip_runtime.h>

#define C_DIM 19
#define G_DIM 8
#define H_DIM 512
#define W_DIM 512
#define B_DIM 4
#define PLANE (H_DIM * W_DIM)
#define NPIX  (B_DIM * PLANE)
#define NT    256

__device__ __forceinline__ unsigned bf16rne(float f) {
    unsigned x = __float_as_uint(f);
    return (x + 0x7fffu + ((x >> 16) & 1u)) >> 16;
}
__device__ __forceinline__ float up_lo(unsigned u) { return __uint_as_float(u << 16); }
__device__ __forceinline__ float up_hi(unsigned u) { return __uint_as_float(u & 0xffff0000u); }

// E = softmax(100*matrix over g): E4[c][0]=g0..3, E4[c][1]=g4..7
__device__ __forceinline__ void build_E(const float* __restrict__ matrix,
                                        float4 (*E4)[2], int tid) {
    if (tid < C_DIM) {
        const int c = tid;
        float m[G_DIM];
        float mx = -1e30f;
        #pragma unroll
        for (int g = 0; g < G_DIM; ++g) {
            m[g] = 100.0f * matrix[g * C_DIM + c];
            mx = fmaxf(mx, m[g]);
        }
        float s = 0.0f;
        #pragma unroll
        for (int g = 0; g < G_DIM; ++g) { m[g] = __expf(m[g] - mx); s += m[g]; }
        const float inv = 1.0f / s;
        E4[c][0] = make_float4(m[0]*inv, m[1]*inv, m[2]*inv, m[3]*inv);
        E4[c][1] = make_float4(m[4]*inv, m[5]*inv, m[6]*inv, m[7]*inv);
    }
    __syncthreads();
}

// ---- K1: softmax over C + encode to G for 4 px/thread; Qg packed [b][h][w][g] bf16 ----
__global__ __launch_bounds__(NT)
void qg_encode(const float* __restrict__ logit,
               const float* __restrict__ matrix,
               uint4* __restrict__ Qg)
{
    __shared__ float4 E4[C_DIM][2];
    build_E(matrix, E4, threadIdx.x);

    const int t   = blockIdx.x * NT + threadIdx.x;   // NPIX/4 threads
    const int px0 = t * 4;
    const int b   = px0 >> 18;
    const int pix = px0 & (PLANE - 1);
    const float* __restrict__ p = logit + (size_t)b * C_DIM * PLANE + pix;

    float eg[G_DIM][4];
    #pragma unroll
    for (int g = 0; g < G_DIM; ++g)
        #pragma unroll
        for (int j = 0; j < 4; ++j) eg[g][j] = 0.0f;
    float s[4] = {0.f, 0.f, 0.f, 0.f};

    #pragma unroll
    for (int c = 0; c < C_DIM; ++c) {
        const float4 lv = *(const float4*)(p + (size_t)c * PLANE);
        const float e0v = __expf(lv.x), e1v = __expf(lv.y),
                    e2v = __expf(lv.z), e3v = __expf(lv.w);
        const float ev[4] = {e0v, e1v, e2v, e3v};
        const float4 E0 = E4[c][0];
        const float4 E1 = E4[c][1];
        #pragma unroll
        for (int j = 0; j < 4; ++j) {
            s[j] += ev[j];
            eg[0][j] = fmaf(E0.x, ev[j], eg[0][j]);
            eg[1][j] = fmaf(E0.y, ev[j], eg[1][j]);
            eg[2][j] = fmaf(E0.z, ev[j], eg[2][j]);
            eg[3][j] = fmaf(E0.w, ev[j], eg[3][j]);
            eg[4][j] = fmaf(E1.x, ev[j], eg[4][j]);
            eg[5][j] = fmaf(E1.y, ev[j], eg[5][j]);
            eg[6][j] = fmaf(E1.z, ev[j], eg[6][j]);
            eg[7][j] = fmaf(E1.w, ev[j], eg[7][j]);
        }
    }
    #pragma unroll
    for (int j = 0; j < 4; ++j) {
        const float inv = 1.0f / s[j];
        uint4 u;
        u.x = bf16rne(eg[0][j]*inv) | (bf16rne(eg[1][j]*inv) << 16);
        u.y = bf16rne(eg[2][j]*inv) | (bf16rne(eg[3][j]*inv) << 16);
        u.z = bf16rne(eg[4][j]*inv) | (bf16rne(eg[5][j]*inv) << 16);
        u.w = bf16rne(eg[6][j]*inv) | (bf16rne(eg[7][j]*inv) << 16);
        Qg[px0 + j] = u;
    }
}

// ---- K2: 9-tap dynamic filter + decode + subtract, 4 px/thread ----
__global__ __launch_bounds__(NT, 4)
void crf_decode(const float* __restrict__ F,
                const float* __restrict__ logit,
                const float* __restrict__ matrix,
                const uint4* __restrict__ Qg,
                float* __restrict__ out)
{
    __shared__ float4 E4[C_DIM][2];
    build_E(matrix, E4, threadIdx.x);

    // XCD-chunked bijective swizzle (1024 blocks, 1024 % 8 == 0)
    const int bid = blockIdx.x;
    const int swz = (bid & 7) * (NPIX / (4 * NT) / 8) + (bid >> 3);
    const int t   = swz * NT + threadIdx.x;
    const int px0 = t * 4;
    const int b   = px0 >> 18;
    const int pix = px0 & (PLANE - 1);
    const int y   = pix >> 9;
    const int x   = pix & (W_DIM - 1);          // multiple of 4

    const uint4* __restrict__ Qb = Qg + (size_t)b * PLANE;
    const float* __restrict__ Fp = F + (size_t)b * 9 * PLANE + pix;

    float og[G_DIM][4];
    #pragma unroll
    for (int g = 0; g < G_DIM; ++g)
        #pragma unroll
        for (int j = 0; j < 4; ++j) og[g][j] = 0.0f;

    #pragma unroll
    for (int dyi = 0; dyi < 3; ++dyi) {
        const int ry  = y + dyi - 1;
        const bool vy = (ry >= 0) & (ry < H_DIM);
        const int rcl = min(max(ry, 0), H_DIM - 1);
        const uint4* __restrict__ Qr = Qb + (size_t)rcl * W_DIM;

        uint4 q[6];                              // columns x-1 .. x+4 (clamped)
        q[0] = Qr[max(x - 1, 0)];
        q[1] = Qr[x];
        q[2] = Qr[x + 1];
        q[3] = Qr[x + 2];
        q[4] = Qr[x + 3];
        q[5] = Qr[min(x + 4, W_DIM - 1)];

        #pragma unroll
        for (int dxi = 0; dxi < 3; ++dxi) {
            const int k = dyi * 3 + dxi;
            const float4 wk4 = *(const float4*)(Fp + (size_t)k * PLANE);
            const float wkv[4] = {wk4.x, wk4.y, wk4.z, wk4.w};
            #pragma unroll
            for (int j = 0; j < 4; ++j) {
                const int col = x + j + dxi - 1;
                const bool v = vy & (col >= 0) & (col < W_DIM);
                const float wv = v ? wkv[j] : 0.0f;
                const uint4 qv = q[j + dxi];
                og[0][j] = fmaf(wv, up_lo(qv.x), og[0][j]);
                og[1][j] = fmaf(wv, up_hi(qv.x), og[1][j]);
                og[2][j] = fmaf(wv, up_lo(qv.y), og[2][j]);
                og[3][j] = fmaf(wv, up_hi(qv.y), og[3][j]);
                og[4][j] = fmaf(wv, up_lo(qv.z), og[4][j]);
                og[5][j] = fmaf(wv, up_hi(qv.z), og[5][j]);
                og[6][j] = fmaf(wv, up_lo(qv.w), og[6][j]);
                og[7][j] = fmaf(wv, up_hi(qv.w), og[7][j]);
            }
        }
    }

    const float* __restrict__ lp = logit + (size_t)b * C_DIM * PLANE + pix;
    float* __restrict__ op = out + (size_t)b * C_DIM * PLANE + pix;
    #pragma unroll
    for (int c = 0; c < C_DIM; ++c) {
        const float4 E0 = E4[c][0];
        const float4 E1 = E4[c][1];
        const float4 lv = *(const float4*)(lp + (size_t)c * PLANE);
        float d[4];
        #pragma unroll
        for (int j = 0; j < 4; ++j) {
            float dec = og[0][j] * E0.x;
            dec = fmaf(og[1][j], E0.y, dec);
            dec = fmaf(og[2][j], E0.z, dec);
            dec = fmaf(og[3][j], E0.w, dec);
            dec = fmaf(og[4][j], E1.x, dec);
            dec = fmaf(og[5][j], E1.y, dec);
            dec = fmaf(og[6][j], E1.z, dec);
            dec = fmaf(og[7][j], E1.w, dec);
            d[j] = dec;
        }
        float4 o;
        o.x = lv.x - d[0];
        o.y = lv.y - d[1];
        o.z = lv.z - d[2];
        o.w = lv.w - d[3];
        *(float4*)(op + (size_t)c * PLANE) = o;
    }
}

extern "C" void kernel_launch(void* const* d_in, const int* in_sizes, int n_in,
                              void* d_out, int out_size, void* d_ws, size_t ws_size,
                              hipStream_t stream) {
    const float* F      = (const float*)d_in[0];   // [4, 9, 512, 512]
    const float* logit  = (const float*)d_in[1];   // [4, 19, 512, 512]
    const float* matrix = (const float*)d_in[2];   // [8, 19, 1, 1]
    float* out = (float*)d_out;                    // [4, 19, 512, 512]
    uint4* Qg = (uint4*)d_ws;                      // 16.8 MB: [4][512][512] x 8 bf16

    qg_encode <<<NPIX / (4 * NT), NT, 0, stream>>>(logit, matrix, Qg);
    crf_decode<<<NPIX / (4 * NT), NT, 0, stream>>>(F, logit, matrix, Qg, out);
}

// Round 6
// 55.052 us; speedup vs baseline: 1.0180x; 1.0180x over previous
//
#include <hip/hip_runtime.h>

#define C_DIM 19
#define G_DIM 8
#define H_DIM 512
#define W_DIM 512
#define B_DIM 4
#define PLANE (H_DIM * W_DIM)
#define NPIX  (B_DIM * PLANE)
#define NT    256

__device__ __forceinline__ unsigned bf16rne(float f) {
    unsigned x = __float_as_uint(f);
    return (x + 0x7fffu + ((x >> 16) & 1u)) >> 16;
}
__device__ __forceinline__ float up_lo(unsigned u) { return __uint_as_float(u << 16); }
__device__ __forceinline__ float up_hi(unsigned u) { return __uint_as_float(u & 0xffff0000u); }

// E = softmax(100*matrix over g): E4[c][0]=g0..3, E4[c][1]=g4..7
__device__ __forceinline__ void build_E(const float* __restrict__ matrix,
                                        float4 (*E4)[2], int tid) {
    if (tid < C_DIM) {
        const int c = tid;
        float m[G_DIM];
        float mx = -1e30f;
        #pragma unroll
        for (int g = 0; g < G_DIM; ++g) {
            m[g] = 100.0f * matrix[g * C_DIM + c];
            mx = fmaxf(mx, m[g]);
        }
        float s = 0.0f;
        #pragma unroll
        for (int g = 0; g < G_DIM; ++g) { m[g] = __expf(m[g] - mx); s += m[g]; }
        const float inv = 1.0f / s;
        E4[c][0] = make_float4(m[0]*inv, m[1]*inv, m[2]*inv, m[3]*inv);
        E4[c][1] = make_float4(m[4]*inv, m[5]*inv, m[6]*inv, m[7]*inv);
    }
    __syncthreads();
}

// ---- K1: softmax over C + encode to G, 2 px/thread; Qg packed [b][h][w][g] bf16 ----
__global__ __launch_bounds__(NT, 4)
void qg_encode(const float* __restrict__ logit,
               const float* __restrict__ matrix,
               uint4* __restrict__ Qg)
{
    __shared__ float4 E4[C_DIM][2];
    build_E(matrix, E4, threadIdx.x);

    const int t   = blockIdx.x * NT + threadIdx.x;   // NPIX/2 threads
    const int px0 = t * 2;
    const int b   = px0 >> 18;
    const int pix = px0 & (PLANE - 1);
    const float* __restrict__ p = logit + (size_t)b * C_DIM * PLANE + pix;

    float eg[G_DIM][2];
    #pragma unroll
    for (int g = 0; g < G_DIM; ++g) { eg[g][0] = 0.0f; eg[g][1] = 0.0f; }
    float s0 = 0.0f, s1 = 0.0f;

    #pragma unroll
    for (int c = 0; c < C_DIM; ++c) {
        const float2 lv = *(const float2*)(p + (size_t)c * PLANE);
        const float e0 = __expf(lv.x);
        const float e1 = __expf(lv.y);
        s0 += e0; s1 += e1;
        const float4 E0 = E4[c][0];
        const float4 E1 = E4[c][1];
        eg[0][0] = fmaf(E0.x, e0, eg[0][0]);  eg[0][1] = fmaf(E0.x, e1, eg[0][1]);
        eg[1][0] = fmaf(E0.y, e0, eg[1][0]);  eg[1][1] = fmaf(E0.y, e1, eg[1][1]);
        eg[2][0] = fmaf(E0.z, e0, eg[2][0]);  eg[2][1] = fmaf(E0.z, e1, eg[2][1]);
        eg[3][0] = fmaf(E0.w, e0, eg[3][0]);  eg[3][1] = fmaf(E0.w, e1, eg[3][1]);
        eg[4][0] = fmaf(E1.x, e0, eg[4][0]);  eg[4][1] = fmaf(E1.x, e1, eg[4][1]);
        eg[5][0] = fmaf(E1.y, e0, eg[5][0]);  eg[5][1] = fmaf(E1.y, e1, eg[5][1]);
        eg[6][0] = fmaf(E1.z, e0, eg[6][0]);  eg[6][1] = fmaf(E1.z, e1, eg[6][1]);
        eg[7][0] = fmaf(E1.w, e0, eg[7][0]);  eg[7][1] = fmaf(E1.w, e1, eg[7][1]);
    }
    {
        const float inv = 1.0f / s0;
        uint4 u;
        u.x = bf16rne(eg[0][0]*inv) | (bf16rne(eg[1][0]*inv) << 16);
        u.y = bf16rne(eg[2][0]*inv) | (bf16rne(eg[3][0]*inv) << 16);
        u.z = bf16rne(eg[4][0]*inv) | (bf16rne(eg[5][0]*inv) << 16);
        u.w = bf16rne(eg[6][0]*inv) | (bf16rne(eg[7][0]*inv) << 16);
        Qg[px0] = u;
    }
    {
        const float inv = 1.0f / s1;
        uint4 u;
        u.x = bf16rne(eg[0][1]*inv) | (bf16rne(eg[1][1]*inv) << 16);
        u.y = bf16rne(eg[2][1]*inv) | (bf16rne(eg[3][1]*inv) << 16);
        u.z = bf16rne(eg[4][1]*inv) | (bf16rne(eg[5][1]*inv) << 16);
        u.w = bf16rne(eg[6][1]*inv) | (bf16rne(eg[7][1]*inv) << 16);
        Qg[px0 + 1] = u;
    }
}

// ---- K2: 9-tap dynamic filter + decode + subtract, 2 px/thread ----
__global__ __launch_bounds__(NT, 4)
void crf_decode(const float* __restrict__ F,
                const float* __restrict__ logit,
                const float* __restrict__ matrix,
                const uint4* __restrict__ Qg,
                float* __restrict__ out)
{
    __shared__ float4 E4[C_DIM][2];
    build_E(matrix, E4, threadIdx.x);

    // XCD-chunked bijective swizzle (2048 blocks, 2048 % 8 == 0)
    const int bid = blockIdx.x;
    const int swz = (bid & 7) * (NPIX / (2 * NT) / 8) + (bid >> 3);
    const int t   = swz * NT + threadIdx.x;
    const int px0 = t * 2;
    const int b   = px0 >> 18;
    const int pix = px0 & (PLANE - 1);
    const int y   = pix >> 9;
    const int x   = pix & (W_DIM - 1);          // multiple of 2

    const uint4* __restrict__ Qb = Qg + (size_t)b * PLANE;
    const float* __restrict__ Fp = F + (size_t)b * 9 * PLANE + pix;

    float og[G_DIM][2];
    #pragma unroll
    for (int g = 0; g < G_DIM; ++g) { og[g][0] = 0.0f; og[g][1] = 0.0f; }

    #pragma unroll
    for (int dyi = 0; dyi < 3; ++dyi) {
        const int ry  = y + dyi - 1;
        const bool vy = (ry >= 0) & (ry < H_DIM);
        const int rcl = min(max(ry, 0), H_DIM - 1);
        const uint4* __restrict__ Qr = Qb + (size_t)rcl * W_DIM;

        uint4 q[4];                              // columns x-1 .. x+2 (clamped)
        q[0] = Qr[max(x - 1, 0)];
        q[1] = Qr[x];
        q[2] = Qr[x + 1];
        q[3] = Qr[min(x + 2, W_DIM - 1)];

        #pragma unroll
        for (int dxi = 0; dxi < 3; ++dxi) {
            const int k = dyi * 3 + dxi;
            const float2 wk2 = *(const float2*)(Fp + (size_t)k * PLANE);
            const float wkv[2] = {wk2.x, wk2.y};
            #pragma unroll
            for (int j = 0; j < 2; ++j) {
                const int col = x + j + dxi - 1;
                const bool v = vy & (col >= 0) & (col < W_DIM);
                const float wv = v ? wkv[j] : 0.0f;
                const uint4 qv = q[j + dxi];
                og[0][j] = fmaf(wv, up_lo(qv.x), og[0][j]);
                og[1][j] = fmaf(wv, up_hi(qv.x), og[1][j]);
                og[2][j] = fmaf(wv, up_lo(qv.y), og[2][j]);
                og[3][j] = fmaf(wv, up_hi(qv.y), og[3][j]);
                og[4][j] = fmaf(wv, up_lo(qv.z), og[4][j]);
                og[5][j] = fmaf(wv, up_hi(qv.z), og[5][j]);
                og[6][j] = fmaf(wv, up_lo(qv.w), og[6][j]);
                og[7][j] = fmaf(wv, up_hi(qv.w), og[7][j]);
            }
        }
    }

    const float* __restrict__ lp = logit + (size_t)b * C_DIM * PLANE + pix;
    float* __restrict__ op = out + (size_t)b * C_DIM * PLANE + pix;
    #pragma unroll
    for (int c = 0; c < C_DIM; ++c) {
        const float4 E0 = E4[c][0];
        const float4 E1 = E4[c][1];
        const float2 lv = *(const float2*)(lp + (size_t)c * PLANE);
        float d[2];
        #pragma unroll
        for (int j = 0; j < 2; ++j) {
            float dec = og[0][j] * E0.x;
            dec = fmaf(og[1][j], E0.y, dec);
            dec = fmaf(og[2][j], E0.z, dec);
            dec = fmaf(og[3][j], E0.w, dec);
            dec = fmaf(og[4][j], E1.x, dec);
            dec = fmaf(og[5][j], E1.y, dec);
            dec = fmaf(og[6][j], E1.z, dec);
            dec = fmaf(og[7][j], E1.w, dec);
            d[j] = dec;
        }
        float2 o;
        o.x = lv.x - d[0];
        o.y = lv.y - d[1];
        *(float2*)(op + (size_t)c * PLANE) = o;
    }
}

extern "C" void kernel_launch(void* const* d_in, const int* in_sizes, int n_in,
                              void* d_out, int out_size, void* d_ws, size_t ws_size,
                              hipStream_t stream) {
    const float* F      = (const float*)d_in[0];   // [4, 9, 512, 512]
    const float* logit  = (const float*)d_in[1];   // [4, 19, 512, 512]
    const float* matrix = (const float*)d_in[2];   // [8, 19, 1, 1]
    float* out = (float*)d_out;                    // [4, 19, 512, 512]
    uint4* Qg = (uint4*)d_ws;                      // 16.8 MB: [4][512][512] x 8 bf16

    qg_encode <<<NPIX / (2 * NT), NT, 0, stream>>>(logit, matrix, Qg);
    crf_decode<<<NPIX / (2 * NT), NT, 0, stream>>>(F, logit, matrix, Qg, out);
}

// Round 7
// 53.231 us; speedup vs baseline: 1.0528x; 1.0342x over previous
//
#include <hip/hip_runtime.h>

#define C_DIM 19
#define G_DIM 8
#define H_DIM 512
#define W_DIM 512
#define B_DIM 4
#define PLANE (H_DIM * W_DIM)
#define NPIX  (B_DIM * PLANE)
#define NT    256
#define TLX   64
#define TLY   8
#define HXX   (TLX + 2)   // 66
#define HYY   (TLY + 2)   // 10

__device__ __forceinline__ unsigned bf16rne(float f) {
    unsigned x = __float_as_uint(f);
    return (x + 0x7fffu + ((x >> 16) & 1u)) >> 16;
}
__device__ __forceinline__ float up_lo(unsigned u) { return __uint_as_float(u << 16); }
__device__ __forceinline__ float up_hi(unsigned u) { return __uint_as_float(u & 0xffff0000u); }

// E = softmax(100*matrix over g): E4[c][0]=g0..3, E4[c][1]=g4..7.  NO sync inside.
__device__ __forceinline__ void build_E_nosync(const float* __restrict__ matrix,
                                               float4 (*E4)[2], int tid) {
    if (tid < C_DIM) {
        const int c = tid;
        float m[G_DIM];
        float mx = -1e30f;
        #pragma unroll
        for (int g = 0; g < G_DIM; ++g) {
            m[g] = 100.0f * matrix[g * C_DIM + c];
            mx = fmaxf(mx, m[g]);
        }
        float s = 0.0f;
        #pragma unroll
        for (int g = 0; g < G_DIM; ++g) { m[g] = __expf(m[g] - mx); s += m[g]; }
        const float inv = 1.0f / s;
        E4[c][0] = make_float4(m[0]*inv, m[1]*inv, m[2]*inv, m[3]*inv);
        E4[c][1] = make_float4(m[4]*inv, m[5]*inv, m[6]*inv, m[7]*inv);
    }
}

// ---- K1: softmax over C + encode to G, 2 px/thread; Qg packed [b][h][w][g] bf16 ----
__global__ __launch_bounds__(NT, 4)
void qg_encode(const float* __restrict__ logit,
               const float* __restrict__ matrix,
               uint4* __restrict__ Qg)
{
    __shared__ float4 E4[C_DIM][2];
    build_E_nosync(matrix, E4, threadIdx.x);
    __syncthreads();

    // same XCD-chunked swizzle as K2 so producer/consumer share an XCD L2
    const int bid = blockIdx.x;
    const int swz = (bid & 7) * (NPIX / (2 * NT) / 8) + (bid >> 3);
    const int t   = swz * NT + threadIdx.x;
    const int px0 = t * 2;
    const int b   = px0 >> 18;
    const int pix = px0 & (PLANE - 1);
    const float* __restrict__ p = logit + (size_t)b * C_DIM * PLANE + pix;

    float eg[G_DIM][2];
    #pragma unroll
    for (int g = 0; g < G_DIM; ++g) { eg[g][0] = 0.0f; eg[g][1] = 0.0f; }
    float s0 = 0.0f, s1 = 0.0f;

    #pragma unroll
    for (int c = 0; c < C_DIM; ++c) {
        const float2 lv = *(const float2*)(p + (size_t)c * PLANE);
        const float e0 = __expf(lv.x);
        const float e1 = __expf(lv.y);
        s0 += e0; s1 += e1;
        const float4 E0 = E4[c][0];
        const float4 E1 = E4[c][1];
        eg[0][0] = fmaf(E0.x, e0, eg[0][0]);  eg[0][1] = fmaf(E0.x, e1, eg[0][1]);
        eg[1][0] = fmaf(E0.y, e0, eg[1][0]);  eg[1][1] = fmaf(E0.y, e1, eg[1][1]);
        eg[2][0] = fmaf(E0.z, e0, eg[2][0]);  eg[2][1] = fmaf(E0.z, e1, eg[2][1]);
        eg[3][0] = fmaf(E0.w, e0, eg[3][0]);  eg[3][1] = fmaf(E0.w, e1, eg[3][1]);
        eg[4][0] = fmaf(E1.x, e0, eg[4][0]);  eg[4][1] = fmaf(E1.x, e1, eg[4][1]);
        eg[5][0] = fmaf(E1.y, e0, eg[5][0]);  eg[5][1] = fmaf(E1.y, e1, eg[5][1]);
        eg[6][0] = fmaf(E1.z, e0, eg[6][0]);  eg[6][1] = fmaf(E1.z, e1, eg[6][1]);
        eg[7][0] = fmaf(E1.w, e0, eg[7][0]);  eg[7][1] = fmaf(E1.w, e1, eg[7][1]);
    }
    {
        const float inv = 1.0f / s0;
        uint4 u;
        u.x = bf16rne(eg[0][0]*inv) | (bf16rne(eg[1][0]*inv) << 16);
        u.y = bf16rne(eg[2][0]*inv) | (bf16rne(eg[3][0]*inv) << 16);
        u.z = bf16rne(eg[4][0]*inv) | (bf16rne(eg[5][0]*inv) << 16);
        u.w = bf16rne(eg[6][0]*inv) | (bf16rne(eg[7][0]*inv) << 16);
        Qg[px0] = u;
    }
    {
        const float inv = 1.0f / s1;
        uint4 u;
        u.x = bf16rne(eg[0][1]*inv) | (bf16rne(eg[1][1]*inv) << 16);
        u.y = bf16rne(eg[2][1]*inv) | (bf16rne(eg[3][1]*inv) << 16);
        u.z = bf16rne(eg[4][1]*inv) | (bf16rne(eg[5][1]*inv) << 16);
        u.w = bf16rne(eg[6][1]*inv) | (bf16rne(eg[7][1]*inv) << 16);
        Qg[px0 + 1] = u;
    }
}

// ---- K2: LDS-staged 9-tap filter + decode + subtract, 2 px/thread ----
// grid (8, 64, 4): tile = 64x8 px, 256 threads x 2 px.
__global__ __launch_bounds__(NT, 4)
void crf_decode(const float* __restrict__ F,
                const float* __restrict__ logit,
                const float* __restrict__ matrix,
                const uint4* __restrict__ Qg,
                float* __restrict__ out)
{
    __shared__ float4 E4[C_DIM][2];
    __shared__ uint4  Qs[HYY][HXX];   // 10560 B

    const int tid = threadIdx.x;
    build_E_nosync(matrix, E4, tid);

    // XCD-chunked bijective swizzle (2048 blocks, 2048 % 8 == 0)
    const int bid = (blockIdx.z * gridDim.y + blockIdx.y) * gridDim.x + blockIdx.x;
    const int swz = (bid & 7) * 256 + (bid >> 3);
    const int b   = swz >> 9;          // 512 tiles per batch
    const int rem = swz & 511;
    const int tby = rem >> 3;          // 0..63
    const int tbx = rem & 7;           // 0..7

    const int tx2 = tid & 31;          // 0..31 (2 px each)
    const int ty  = tid >> 5;          // 0..7
    const int x   = tbx * TLX + tx2 * 2;
    const int y   = tby * TLY + ty;
    const size_t pix = (size_t)y * W_DIM + x;

    // issue F loads early: their HBM latency hides under LDS staging
    const float* __restrict__ Fp = F + (size_t)b * 9 * PLANE + pix;
    float2 wk[9];
    #pragma unroll
    for (int k = 0; k < 9; ++k) wk[k] = *(const float2*)(Fp + (size_t)k * PLANE);

    // stage Qg halo tile (clamped) into LDS, coalesced rows
    const int y0 = tby * TLY - 1;
    const int x0 = tbx * TLX - 1;
    const uint4* __restrict__ Qb = Qg + (size_t)b * PLANE;
    #pragma unroll
    for (int i = tid; i < HYY * HXX; i += NT) {
        const int r  = i / HXX;
        const int cc = i - r * HXX;
        const int gy = min(max(y0 + r, 0), H_DIM - 1);
        const int gx = min(max(x0 + cc, 0), W_DIM - 1);
        Qs[r][cc] = Qb[(size_t)gy * W_DIM + gx];
    }
    __syncthreads();

    float og[G_DIM][2];
    #pragma unroll
    for (int g = 0; g < G_DIM; ++g) { og[g][0] = 0.0f; og[g][1] = 0.0f; }

    const int lx = tx2 * 2;            // LDS col of (x-1)
    #pragma unroll
    for (int dyi = 0; dyi < 3; ++dyi) {
        const int ry  = y + dyi - 1;
        const bool vy = (ry >= 0) & (ry < H_DIM);
        const uint4 q0 = Qs[ty + dyi][lx];
        const uint4 q1 = Qs[ty + dyi][lx + 1];
        const uint4 q2 = Qs[ty + dyi][lx + 2];
        const uint4 q3 = Qs[ty + dyi][lx + 3];
        const uint4 qv_[4] = {q0, q1, q2, q3};

        #pragma unroll
        for (int dxi = 0; dxi < 3; ++dxi) {
            const int k = dyi * 3 + dxi;
            const float wkv[2] = {wk[k].x, wk[k].y};
            #pragma unroll
            for (int j = 0; j < 2; ++j) {
                const int col = x + j + dxi - 1;
                const bool v = vy & (col >= 0) & (col < W_DIM);
                const float wv = v ? wkv[j] : 0.0f;
                const uint4 qv = qv_[j + dxi];
                og[0][j] = fmaf(wv, up_lo(qv.x), og[0][j]);
                og[1][j] = fmaf(wv, up_hi(qv.x), og[1][j]);
                og[2][j] = fmaf(wv, up_lo(qv.y), og[2][j]);
                og[3][j] = fmaf(wv, up_hi(qv.y), og[3][j]);
                og[4][j] = fmaf(wv, up_lo(qv.z), og[4][j]);
                og[5][j] = fmaf(wv, up_hi(qv.z), og[5][j]);
                og[6][j] = fmaf(wv, up_lo(qv.w), og[6][j]);
                og[7][j] = fmaf(wv, up_hi(qv.w), og[7][j]);
            }
        }
    }

    const float* __restrict__ lp = logit + (size_t)b * C_DIM * PLANE + pix;
    float* __restrict__ op = out + (size_t)b * C_DIM * PLANE + pix;
    #pragma unroll
    for (int c = 0; c < C_DIM; ++c) {
        const float4 E0 = E4[c][0];
        const float4 E1 = E4[c][1];
        const float2 lv = *(const float2*)(lp + (size_t)c * PLANE);
        float d[2];
        #pragma unroll
        for (int j = 0; j < 2; ++j) {
            float dec = og[0][j] * E0.x;
            dec = fmaf(og[1][j], E0.y, dec);
            dec = fmaf(og[2][j], E0.z, dec);
            dec = fmaf(og[3][j], E0.w, dec);
            dec = fmaf(og[4][j], E1.x, dec);
            dec = fmaf(og[5][j], E1.y, dec);
            dec = fmaf(og[6][j], E1.z, dec);
            dec = fmaf(og[7][j], E1.w, dec);
            d[j] = dec;
        }
        float2 o;
        o.x = lv.x - d[0];
        o.y = lv.y - d[1];
        *(float2*)(op + (size_t)c * PLANE) = o;
    }
}

extern "C" void kernel_launch(void* const* d_in, const int* in_sizes, int n_in,
                              void* d_out, int out_size, void* d_ws, size_t ws_size,
                              hipStream_t stream) {
    const float* F      = (const float*)d_in[0];   // [4, 9, 512, 512]
    const float* logit  = (const float*)d_in[1];   // [4, 19, 512, 512]
    const float* matrix = (const float*)d_in[2];   // [8, 19, 1, 1]
    float* out = (float*)d_out;                    // [4, 19, 512, 512]
    uint4* Qg = (uint4*)d_ws;                      // 16.8 MB: [4][512][512] x 8 bf16

    qg_encode <<<NPIX / (2 * NT), NT, 0, stream>>>(logit, matrix, Qg);
    dim3 grid2(W_DIM / TLX, H_DIM / TLY, B_DIM);   // (8, 64, 4) = 2048
    crf_decode<<<grid2, NT, 0, stream>>>(F, logit, matrix, Qg, out);
}